// Round 1
// 73.679 us; speedup vs baseline: 1.0154x; 1.0154x over previous
//
#include <hip/hip_runtime.h>
#include <math.h>

// L=13, M=12, ODD_KS=(1,3,5) -> NK=3
#define LL    13
#define MM    12
#define NKK   3
#define BLOCK 256
#define HALO  24                  // window spans [t-24, t+24]
#define WIN   (BLOCK + 2*HALO)    // 304 samples staged per block
#define DMAX  25                  // d = l + m, m in [0..12]; m==12 is the A tap
#define NW    (DMAX * LL)         // 325 coefficient slots per table

// LDS maps (window base t0-24), i = tid:
//   B/A powers at d -> sP[i + d]       (sample t + d - 24)
//   C   powers at d -> sP[i + d + 24]  (sample t + d)
//   x1(l)  -> sZ[i + l + 12]           x3last(l) -> sZ[i + l + 36]
// Coefficients live in LDS, d-major:
//   sWB[d*13+l] = (m==12 ? A[l] : B[l][m]) triple, m = d - l
//   sWC[d*13+l] = C[l][m] triple (m < 12)
// Hot loop is DS-only: no SMEM in flight -> counted lgkmcnt, no (0)-drains.

__global__ __launch_bounds__(BLOCK)
void gmp_kernel(const float* __restrict__ x,    // (B,T,2)
                const float* __restrict__ Ac,   // (L,NK)
                const float* __restrict__ Bc,   // (L,M,NK)
                const float* __restrict__ Cc,   // (L,M,NK)
                float* __restrict__ out,        // (B,T,2)
                int T, int tilesPerB)
{
    __shared__ float4 sP[WIN];    // {a, a^3, a^5, 0} -> ds_read_b128
    __shared__ float2 sZ[WIN];    // {re, im}         -> ds_read_b64
    __shared__ float4 sWB[NW];    // B/A coefficient quads (broadcast reads)
    __shared__ float4 sWC[NW];    // C coefficient quads

    const int tid = threadIdx.x;
    const int b   = blockIdx.x / tilesPerB;
    const int t0  = (blockIdx.x % tilesPerB) * BLOCK;

    const float* xb = x + (size_t)b * T * 2;

    // --- Stage 304-sample window (circular wrap); powers computed once ---
    for (int j = tid; j < WIN; j += BLOCK) {
        int t = t0 - HALO + j;
        if (t < 0)  t += T;
        if (t >= T) t -= T;
        const float2 z = *(const float2*)(xb + 2 * t);
        float a2 = z.x * z.x + z.y * z.y;
        float a  = sqrtf(a2);
        sZ[j] = z;
        sP[j] = make_float4(a, a * a2, a * a2 * a2, 0.0f);
    }

    // --- Stage coefficients into LDS in consumption order (once/block) ---
    for (int idx = tid; idx < NW; idx += BLOCK) {
        const int d = idx / LL;
        const int l = idx - d * LL;
        const int m = d - l;
        float4 wb = make_float4(0.f, 0.f, 0.f, 0.f);
        float4 wc = make_float4(0.f, 0.f, 0.f, 0.f);
        if (m >= 0 && m <= MM) {
            const float* s = (m == MM) ? (Ac + l * NKK)
                                       : (Bc + (l * MM + m) * NKK);
            wb = make_float4(s[0], s[1], s[2], 0.f);
        }
        if (m >= 0 && m < MM) {
            const float* s = Cc + (l * MM + m) * NKK;
            wc = make_float4(s[0], s[1], s[2], 0.f);
        }
        sWB[idx] = wb;
        sWC[idx] = wc;
    }
    __syncthreads();

    // --- Per-tap coefficient accumulators (registers) ---
    float cB[LL], cC[LL];
    #pragma unroll
    for (int l = 0; l < LL; ++l) { cB[l] = 0.f; cC[l] = 0.f; }

    // d = l + m in [0,24]; A folded in as the m==12 tap of the B table.
    // Fully unrolled: all LDS offsets are compile-time immediates; the
    // coefficient reads are wave-uniform -> conflict-free broadcasts.
    #pragma unroll
    for (int d = 0; d < DMAX; ++d) {
        const float4 p = sP[tid + d];               // B/A-term powers
        const float4 q = sP[tid + d + 24];          // C-term powers
        #pragma unroll
        for (int l = 0; l < LL; ++l) {
            const int m = d - l;                    // folds at compile time
            if (m >= 0 && m <= MM) {
                const float4 w = sWB[d * LL + l];
                cB[l] += w.x * p.x + w.y * p.y + w.z * p.z;
            }
            if (m >= 0 && m < MM) {
                const float4 w = sWC[d * LL + l];
                cC[l] += w.x * q.x + w.y * q.y + w.z * q.z;
            }
        }
    }

    // --- Complex epilogue: sum_l x1*cB[l] + x3_last*cC[l] ---
    float sr = 0.0f, si = 0.0f;
    #pragma unroll
    for (int l = 0; l < LL; ++l) {
        const float2 z1 = sZ[tid + l + 12];
        const float2 z3 = sZ[tid + l + 36];
        sr += z1.x * cB[l] + z3.x * cC[l];
        si += z1.y * cB[l] + z3.y * cC[l];
    }

    const int t = t0 + tid;
    if (t < T) {
        float2* op = (float2*)(out + ((size_t)b * T + t) * 2);
        *op = make_float2(sr, si);                  // global_store_dwordx2
    }
}

extern "C" void kernel_launch(void* const* d_in, const int* in_sizes, int n_in,
                              void* d_out, int out_size, void* d_ws, size_t ws_size,
                              hipStream_t stream)
{
    // Inputs: x (B,T,2) f32, h_0 (B,16) f32 [unused], A_kl (L,NK),
    // B_klm (L,M,NK), C_klm (L,M,NK)
    const float* x  = (const float*)d_in[0];
    const float* Ac = (const float*)d_in[2];
    const float* Bc = (const float*)d_in[3];
    const float* Cc = (const float*)d_in[4];
    float* out = (float*)d_out;

    const int Bsz = in_sizes[1] / 16;               // h_0 is (B,16)
    const int T   = in_sizes[0] / (2 * Bsz);        // x is (B,T,2)
    const int tilesPerB = (T + BLOCK - 1) / BLOCK;  // 32 for T=8192

    dim3 grid(Bsz * tilesPerB);                     // 512 blocks
    dim3 block(BLOCK);
    gmp_kernel<<<grid, block, 0, stream>>>(x, Ac, Bc, Cc, out, T, tilesPerB);
}